// Round 6
// baseline (257.916 us; speedup 1.0000x reference)
//
#include <hip/hip_runtime.h>
#include <stdint.h>
#include <math.h>

#define B_ 4
#define T_ 4096
#define C_ 1024
#define H_ 128

typedef __attribute__((ext_vector_type(8))) short s16x8;   // 8 bf16 (4 VGPRs)
typedef __attribute__((ext_vector_type(4))) float f32x4;   // MFMA accumulator

__device__ __forceinline__ unsigned short f2bf(float f) {
    union { float f; unsigned u; } v; v.f = f;
    unsigned r = v.u + 0x7fffu + ((v.u >> 16) & 1u);
    return (unsigned short)(r >> 16);
}

__device__ __forceinline__ s16x8 as_frag(uint4 u) {
    union { uint4 u; s16x8 s; } v; v.u = u; return v.s;
}

// DPP butterfly reduction across 16 contiguous lanes (VALU-only, off LDS pipe).
#define DPP_STEP(x, ctrl, op)                                                  \
    x = op(x, __int_as_float(__builtin_amdgcn_update_dpp(                      \
               0, __float_as_int(x), ctrl, 0xF, 0xF, true)))

__device__ __forceinline__ float red16_max(float x) {
    DPP_STEP(x, 0xB1, fmaxf); DPP_STEP(x, 0x4E, fmaxf);
    DPP_STEP(x, 0x141, fmaxf); DPP_STEP(x, 0x140, fmaxf);
    return x;
}
__device__ __forceinline__ float addf(float a, float b) { return a + b; }
__device__ __forceinline__ float red16_sum(float x) {
    DPP_STEP(x, 0xB1, addf); DPP_STEP(x, 0x4E, addf);
    DPP_STEP(x, 0x141, addf); DPP_STEP(x, 0x140, addf);
    return x;
}

// softmax scale folded into Q at projection time: 1/sqrt(128) * log2(e)
#define QSC (0.0883883476f * 1.4426950408f)

// ---------------------------------------------------------------------------
// Kernel 1: W [1024][128] fp32 -> Wt [3*128][1024] bf16 (transposed, converted)
// ---------------------------------------------------------------------------
__global__ __launch_bounds__(256) void k_wt(const float* __restrict__ Wk,
                                            const float* __restrict__ Wq,
                                            const float* __restrict__ Wv,
                                            unsigned short* __restrict__ Wt) {
    __shared__ float tile[64][65];
    int w = blockIdx.z;  // 0=K, 1=Q, 2=V
    const float* W = (w == 0) ? Wk : (w == 1) ? Wq : Wv;
    int c0 = blockIdx.x * 64, h0 = blockIdx.y * 64;
    int tid = threadIdx.x;
#pragma unroll
    for (int k = 0; k < 16; k++) {
        int idx = tid + k * 256;
        int r = idx >> 6, c = idx & 63;
        tile[r][c] = W[(size_t)(c0 + r) * H_ + h0 + c];
    }
    __syncthreads();
#pragma unroll
    for (int k = 0; k < 16; k++) {
        int idx = tid + k * 256;
        int hh = idx >> 6, cc = idx & 63;
        Wt[(size_t)(w * H_ + h0 + hh) * C_ + c0 + cc] = f2bf(tile[cc][hh]);
    }
}

// ---------------------------------------------------------------------------
// Kernel 2: fused QKV GEMM — r4 PROVEN version (64-row tiles; r5's 32-row
// variant regressed: too little work per wave to cover fixed latencies).
// 512 blocks: 256 row-tiles (64 rows) x 2 col-halves (192 cols).
// Register ping-pong of x chunk + Wt fragments. bounds(256,2): no spill.
// ---------------------------------------------------------------------------
__global__ __launch_bounds__(256, 2) void k_qkv(const float* __restrict__ x,
                                                const unsigned short* __restrict__ Wt,
                                                unsigned short* __restrict__ Qb,
                                                unsigned short* __restrict__ Kb,
                                                unsigned short* __restrict__ Vt) {
    __shared__ unsigned short a_lds[64 * 72];  // 64 rows x 64 k, stride 72
    int tid = threadIdx.x;
    int wv = tid >> 6, lane = tid & 63, quad = lane >> 4, lo = lane & 15;
    int r0 = blockIdx.x * 64;
    int cb = blockIdx.y;
    int nt0 = wv * 3;

    f32x4 acc[3][4];
#pragma unroll
    for (int i = 0; i < 3; i++)
#pragma unroll
        for (int j = 0; j < 4; j++) acc[i][j] = (f32x4){0.f, 0.f, 0.f, 0.f};

    const int row_s = tid >> 2;
    const int seg_s = (tid & 3) * 16;
    size_t xbase = (size_t)(r0 + row_s) * C_ + seg_s;

    const unsigned short* wp[3];
#pragma unroll
    for (int nt = 0; nt < 3; nt++)
        wp[nt] = Wt + (size_t)(cb * 192 + (nt0 + nt) * 16 + lo) * C_ + quad * 8;

    auto pack_store = [&](const float4 (&f)[4]) {
        uint4 u0, u1;
        u0.x = (unsigned)f2bf(f[0].x) | ((unsigned)f2bf(f[0].y) << 16);
        u0.y = (unsigned)f2bf(f[0].z) | ((unsigned)f2bf(f[0].w) << 16);
        u0.z = (unsigned)f2bf(f[1].x) | ((unsigned)f2bf(f[1].y) << 16);
        u0.w = (unsigned)f2bf(f[1].z) | ((unsigned)f2bf(f[1].w) << 16);
        u1.x = (unsigned)f2bf(f[2].x) | ((unsigned)f2bf(f[2].y) << 16);
        u1.y = (unsigned)f2bf(f[2].z) | ((unsigned)f2bf(f[2].w) << 16);
        u1.z = (unsigned)f2bf(f[3].x) | ((unsigned)f2bf(f[3].y) << 16);
        u1.w = (unsigned)f2bf(f[3].z) | ((unsigned)f2bf(f[3].w) << 16);
        *(uint4*)&a_lds[row_s * 72 + seg_s] = u0;
        *(uint4*)&a_lds[row_s * 72 + seg_s + 8] = u1;
    };
    auto load_x = [&](float4 (&f)[4], int kc) {
        const float* xp = x + xbase + kc * 64;
#pragma unroll
        for (int j = 0; j < 4; j++) f[j] = *(const float4*)(xp + j * 4);
    };
    auto load_b = [&](s16x8 (&b)[3][2], int kc) {
#pragma unroll
        for (int nt = 0; nt < 3; nt++)
#pragma unroll
            for (int kh = 0; kh < 2; kh++)
                b[nt][kh] = *(const s16x8*)(wp[nt] + kc * 64 + kh * 32);
    };
    auto gemm = [&](const s16x8 (&b)[3][2]) {
        s16x8 af[4][2];
#pragma unroll
        for (int mt = 0; mt < 4; mt++)
#pragma unroll
            for (int kh = 0; kh < 2; kh++)
                af[mt][kh] = *(const s16x8*)&a_lds[(mt * 16 + lo) * 72 + kh * 32 + quad * 8];
#pragma unroll
        for (int nt = 0; nt < 3; nt++)
#pragma unroll
            for (int kh = 0; kh < 2; kh++)
#pragma unroll
                for (int mt = 0; mt < 4; mt++)
                    acc[nt][mt] = __builtin_amdgcn_mfma_f32_16x16x32_bf16(
                        af[mt][kh], b[nt][kh], acc[nt][mt], 0, 0, 0);
    };

    float4 xa[4], xb[4];
    s16x8 ba[3][2], bb[3][2];
    load_x(xa, 0);
    load_b(ba, 0);

    for (int kc2 = 0; kc2 < 8; kc2++) {
        int e = kc2 * 2;
        pack_store(xa);
        load_x(xb, e + 1);
        __syncthreads();
        load_b(bb, e + 1);
        gemm(ba);
        __syncthreads();
        pack_store(xb);
        if (kc2 < 7) load_x(xa, e + 2);
        __syncthreads();
        if (kc2 < 7) load_b(ba, e + 2);
        gemm(bb);
        __syncthreads();
    }

    // Epilogue. C-layout: row = mt*16 + quad*4 + r, col = cb*192 + (nt0+nt)*16 + lo
#pragma unroll
    for (int nt = 0; nt < 3; nt++) {
        int col = cb * 192 + (nt0 + nt) * 16 + lo;
        int w = col >> 7, h = col & 127;
#pragma unroll
        for (int mt = 0; mt < 4; mt++) {
            int mrow = r0 + mt * 16 + quad * 4;
            if (w == 2) {
                int b = mrow >> 12, t = mrow & 4095;
                uint2 pk;
                pk.x = (unsigned)f2bf(acc[nt][mt][0]) | ((unsigned)f2bf(acc[nt][mt][1]) << 16);
                pk.y = (unsigned)f2bf(acc[nt][mt][2]) | ((unsigned)f2bf(acc[nt][mt][3]) << 16);
                *(uint2*)(Vt + (size_t)(b * H_ + h) * T_ + t) = pk;
            } else if (w == 1) {
                unsigned short* dst = Qb + (size_t)mrow * H_ + h;
#pragma unroll
                for (int r = 0; r < 4; r++)
                    dst[(size_t)r * H_] = f2bf(acc[nt][mt][r] * QSC);
            } else {
                unsigned short* dst = Kb + (size_t)mrow * H_ + h;
#pragma unroll
                for (int r = 0; r < 4; r++)
                    dst[(size_t)r * H_] = f2bf(acc[nt][mt][r]);
            }
        }
    }
}

// ---------------------------------------------------------------------------
// Kernel 3: causal flash attention, split-KV, register prefetch (explicit
// scalars), DPP softmax. This round: bounds(256,4) (r4 used only 84 VGPRs,
// fits the 128 cap -> 4 blocks/CU now reachable, LDS 40KB allows exactly 4);
// P-pack by truncation (1 VALU op); wave-uniform rescale-skip.
// ---------------------------------------------------------------------------
#define LOAD_KV(kv0)                                                            \
    do {                                                                        \
        const uint4* kg = (const uint4*)(Kb + (size_t)(batch * T_ + (kv0) + srow_k) * H_); \
        pk0 = kg[sseg_k + 0]; pk1 = kg[sseg_k + 1];                             \
        pk2 = kg[sseg_k + 2]; pk3 = kg[sseg_k + 3];                             \
        const uint4* vg = (const uint4*)(Vt + (size_t)(batch * H_ + srow_v) * T_ + (kv0)); \
        pv0 = vg[sseg_v + 0]; pv1 = vg[sseg_v + 1];                             \
        pv2 = vg[sseg_v + 2]; pv3 = vg[sseg_v + 3];                             \
    } while (0)

template <int NSPLIT>
__global__ __launch_bounds__(256, 4) void k_attn(const unsigned short* __restrict__ Qb,
                                                 const unsigned short* __restrict__ Kb,
                                                 const unsigned short* __restrict__ Vt,
                                                 float* __restrict__ Opart,
                                                 float* __restrict__ Mpart,
                                                 float* __restrict__ Lpart,
                                                 float* __restrict__ out) {
    __shared__ uint4 kbuf[64 * 16];
    __shared__ uint4 vbuf[128 * 8];
    __shared__ unsigned short pbuf[4][16 * 64];

    int tid = threadIdx.x;
    int wv = tid >> 6, lane = tid & 63, quad = lane >> 4, lo = lane & 15;

    int id = blockIdx.x;
    int qt = 63 - id / (4 * NSPLIT);   // largest-first
    int rem = id % (4 * NSPLIT);
    int batch = rem / NSPLIT;
    int split = rem % NSPLIT;
    int m0 = qt * 64 + wv * 16;

    s16x8 qf[4];
    size_t qrow = (size_t)(batch * T_ + m0 + lo) * H_;
#pragma unroll
    for (int ks = 0; ks < 4; ks++)
        qf[ks] = *(const s16x8*)(Qb + qrow + ks * 32 + quad * 8);

    f32x4 acc_o[8];
#pragma unroll
    for (int o = 0; o < 8; o++) acc_o[o] = (f32x4){0.f, 0.f, 0.f, 0.f};
    float m_i[4], l_i[4];
#pragma unroll
    for (int r = 0; r < 4; r++) { m_i[r] = -INFINITY; l_i[r] = 0.f; }

    const int srow_k = tid >> 2, sseg_k = (tid & 3) * 4;
    const int srow_v = tid >> 1, sseg_v = (tid & 1) * 4;

    uint4 pk0, pk1, pk2, pk3, pv0, pv1, pv2, pv3;
    if (split <= qt) LOAD_KV(split * 64);

    for (int t = split; t <= qt; t += NSPLIT) {
        int kv0 = t * 64;
        kbuf[srow_k * 16 + ((sseg_k + 0) ^ (srow_k & 15))] = pk0;
        kbuf[srow_k * 16 + ((sseg_k + 1) ^ (srow_k & 15))] = pk1;
        kbuf[srow_k * 16 + ((sseg_k + 2) ^ (srow_k & 15))] = pk2;
        kbuf[srow_k * 16 + ((sseg_k + 3) ^ (srow_k & 15))] = pk3;
        vbuf[srow_v * 8 + ((sseg_v + 0) ^ (srow_v & 7))] = pv0;
        vbuf[srow_v * 8 + ((sseg_v + 1) ^ (srow_v & 7))] = pv1;
        vbuf[srow_v * 8 + ((sseg_v + 2) ^ (srow_v & 7))] = pv2;
        vbuf[srow_v * 8 + ((sseg_v + 3) ^ (srow_v & 7))] = pv3;
        __syncthreads();
        if (t + NSPLIT <= qt) LOAD_KV((t + NSPLIT) * 64);

        // S = Q K^T (logits already in log2 domain; Q pre-scaled)
        f32x4 s_acc[4];
#pragma unroll
        for (int nt = 0; nt < 4; nt++) s_acc[nt] = (f32x4){0.f, 0.f, 0.f, 0.f};
#pragma unroll
        for (int ks = 0; ks < 4; ks++) {
#pragma unroll
            for (int nt = 0; nt < 4; nt++) {
                s16x8 kf = as_frag(kbuf[(nt * 16 + lo) * 16 + ((ks * 4 + quad) ^ lo)]);
                s_acc[nt] = __builtin_amdgcn_mfma_f32_16x16x32_bf16(qf[ks], kf, s_acc[nt], 0, 0, 0);
            }
        }

        float p[4][4];
        bool diag = (t == qt);
#pragma unroll
        for (int nt = 0; nt < 4; nt++)
#pragma unroll
            for (int r = 0; r < 4; r++) {
                float sv = s_acc[nt][r];
                if (diag) {
                    int colg = kv0 + nt * 16 + lo;
                    int rowg = m0 + quad * 4 + r;
                    if (colg > rowg) sv = -INFINITY;
                }
                p[nt][r] = sv;
            }
        float mnew[4];
        bool upd = false;
#pragma unroll
        for (int r = 0; r < 4; r++) {
            float mx = fmaxf(fmaxf(p[0][r], p[1][r]), fmaxf(p[2][r], p[3][r]));
            mx = red16_max(mx);
            mnew[r] = fmaxf(m_i[r], mx);
            upd |= (mnew[r] > m_i[r]);
        }
        // wave-uniform rescale-skip: running max usually stops moving after
        // the first few tiles -> most iterations skip the alpha rescale.
        if (__any(upd)) {
#pragma unroll
            for (int r = 0; r < 4; r++) {
                float alpha = exp2f(m_i[r] - mnew[r]);
                l_i[r] *= alpha;
                m_i[r] = mnew[r];
#pragma unroll
                for (int o = 0; o < 8; o++) acc_o[o][r] *= alpha;
            }
        }
        float rs[4] = {0.f, 0.f, 0.f, 0.f};
#pragma unroll
        for (int nt = 0; nt < 4; nt++)
#pragma unroll
            for (int r = 0; r < 4; r++) {
                float pv = exp2f(p[nt][r] - mnew[r]);
                p[nt][r] = pv;
                rs[r] += pv;
            }
#pragma unroll
        for (int r = 0; r < 4; r++) l_i[r] += red16_sum(rs[r]);

        // P: C-layout -> A-layout via per-wave LDS. Truncation pack (P in
        // [0,1], err <= 2^-9 — threshold has 3.6x headroom): 1 VALU op.
        unsigned short* pb = pbuf[wv];
#pragma unroll
        for (int nt = 0; nt < 4; nt++)
#pragma unroll
            for (int r = 0; r < 4; r++) {
                int prow = quad * 4 + r;
                int col = nt * 16 + lo;
                int seg = col >> 3, off = col & 7;
                pb[prow * 64 + ((seg ^ (prow & 7)) << 3) + off] =
                    (unsigned short)(__float_as_uint(p[nt][r]) >> 16);
            }
        s16x8 pf[2];
#pragma unroll
        for (int kss = 0; kss < 2; kss++) {
            int seg = kss * 4 + quad;
            pf[kss] = *(const s16x8*)&pb[lo * 64 + ((seg ^ (lo & 7)) << 3)];
        }

#pragma unroll
        for (int kss = 0; kss < 2; kss++)
#pragma unroll
            for (int o = 0; o < 8; o++) {
                int vrow = o * 16 + lo;
                s16x8 vf = as_frag(vbuf[vrow * 8 + ((kss * 4 + quad) ^ (vrow & 7))]);
                acc_o[o] = __builtin_amdgcn_mfma_f32_16x16x32_bf16(pf[kss], vf, acc_o[o], 0, 0, 0);
            }
        __syncthreads();
    }

    if (NSPLIT == 1) {
        float inv[4];
#pragma unroll
        for (int r = 0; r < 4; r++) inv[r] = 1.0f / l_i[r];
#pragma unroll
        for (int o = 0; o < 8; o++)
#pragma unroll
            for (int r = 0; r < 4; r++) {
                int rowg = batch * T_ + m0 + quad * 4 + r;
                out[(size_t)rowg * H_ + o * 16 + lo] = acc_o[o][r] * inv[r];
            }
    } else {
        float* Op = Opart + (size_t)split * (16384 * 128);
#pragma unroll
        for (int o = 0; o < 8; o++)
#pragma unroll
            for (int r = 0; r < 4; r++) {
                int rowg = batch * T_ + m0 + quad * 4 + r;
                Op[(size_t)rowg * H_ + o * 16 + lo] = acc_o[o][r];
            }
        if (lo == 0) {
#pragma unroll
            for (int r = 0; r < 4; r++) {
                int rowg = batch * T_ + m0 + quad * 4 + r;
                Mpart[split * 16384 + rowg] = m_i[r];
                Lpart[split * 16384 + rowg] = l_i[r];
            }
        }
    }
}

// ---------------------------------------------------------------------------
// Kernel 4: combine split-KV partials. 8 rows/block, float4 per thread.
// ---------------------------------------------------------------------------
template <int NSPLIT>
__global__ __launch_bounds__(256) void k_comb(const float* __restrict__ Opart,
                                              const float* __restrict__ Mpart,
                                              const float* __restrict__ Lpart,
                                              float* __restrict__ out) {
    int tid = threadIdx.x;
    int row = blockIdx.x * 8 + (tid >> 5);
    int h4 = (tid & 31) * 4;
    float m[NSPLIT], l[NSPLIT];
    float M = -INFINITY;
#pragma unroll
    for (int s = 0; s < NSPLIT; s++) {
        m[s] = Mpart[s * 16384 + row];
        l[s] = Lpart[s * 16384 + row];
        M = fmaxf(M, m[s]);
    }
    float4 o = {0.f, 0.f, 0.f, 0.f};
    float den = 0.f;
#pragma unroll
    for (int s = 0; s < NSPLIT; s++) {
        float w = exp2f(m[s] - M);
        den += w * l[s];
        float4 v = *(const float4*)(Opart + ((size_t)s * 16384 + row) * H_ + h4);
        o.x += w * v.x; o.y += w * v.y; o.z += w * v.z; o.w += w * v.w;
    }
    float inv = 1.0f / den;
    float4 r = {o.x * inv, o.y * inv, o.z * inv, o.w * inv};
    *(float4*)(out + (size_t)row * H_ + h4) = r;
}

// ---------------------------------------------------------------------------
extern "C" void kernel_launch(void* const* d_in, const int* in_sizes, int n_in,
                              void* d_out, int out_size, void* d_ws, size_t ws_size,
                              hipStream_t stream) {
    const float* x  = (const float*)d_in[0];
    const float* Wk = (const float*)d_in[1];
    const float* Wq = (const float*)d_in[2];
    const float* Wv = (const float*)d_in[3];
    char* ws = (char*)d_ws;
    unsigned short* Wt = (unsigned short*)ws;                 // 768 KB
    unsigned short* Qb = (unsigned short*)(ws + (1u << 20));  // 4 MB
    unsigned short* Kb = (unsigned short*)(ws + (5u << 20));  // 4 MB
    unsigned short* Vt = (unsigned short*)(ws + (9u << 20));  // 4 MB -> end 13 MB
    float* out = (float*)d_out;

    const size_t SPLIT_O = (size_t)16384 * 128 * 4;  // 8 MB per split
    const size_t base = (size_t)13 << 20;
    const size_t need4 = base + 4 * SPLIT_O + 8 * 65536;
    const size_t need2 = base + 2 * SPLIT_O + 4 * 65536;

    k_wt  <<<dim3(16, 2, 3), 256, 0, stream>>>(Wk, Wq, Wv, Wt);
    k_qkv <<<dim3(256, 2), 256, 0, stream>>>(x, Wt, Qb, Kb, Vt);

    if (ws_size >= need4) {
        float* Op = (float*)(ws + base);
        float* Mp = (float*)(ws + base + 4 * SPLIT_O);
        float* Lp = (float*)(ws + base + 4 * SPLIT_O + 4 * 65536);
        k_attn<4><<<1024, 256, 0, stream>>>(Qb, Kb, Vt, Op, Mp, Lp, out);
        k_comb<4><<<2048, 256, 0, stream>>>(Op, Mp, Lp, out);
    } else if (ws_size >= need2) {
        float* Op = (float*)(ws + base);
        float* Mp = (float*)(ws + base + 2 * SPLIT_O);
        float* Lp = (float*)(ws + base + 2 * SPLIT_O + 2 * 65536);
        k_attn<2><<<512, 256, 0, stream>>>(Qb, Kb, Vt, Op, Mp, Lp, out);
        k_comb<2><<<2048, 256, 0, stream>>>(Op, Mp, Lp, out);
    } else {
        k_attn<1><<<256, 256, 0, stream>>>(Qb, Kb, Vt, nullptr, nullptr, nullptr, out);
    }
}

// Round 7
// 176.350 us; speedup vs baseline: 1.4625x; 1.4625x over previous
//
#include <hip/hip_runtime.h>
#include <stdint.h>
#include <math.h>

#define B_ 4
#define T_ 4096
#define C_ 1024
#define H_ 128

typedef __attribute__((ext_vector_type(8))) short s16x8;   // 8 bf16 (4 VGPRs)
typedef __attribute__((ext_vector_type(4))) float f32x4;   // MFMA accumulator

__device__ __forceinline__ unsigned short f2bf(float f) {
    union { float f; unsigned u; } v; v.f = f;
    unsigned r = v.u + 0x7fffu + ((v.u >> 16) & 1u);
    return (unsigned short)(r >> 16);
}

__device__ __forceinline__ s16x8 as_frag(uint4 u) {
    union { uint4 u; s16x8 s; } v; v.u = u; return v.s;
}

// DPP butterfly reduction across 16 contiguous lanes (VALU-only, off LDS pipe).
#define DPP_STEP(x, ctrl, op)                                                  \
    x = op(x, __int_as_float(__builtin_amdgcn_update_dpp(                      \
               0, __float_as_int(x), ctrl, 0xF, 0xF, true)))

__device__ __forceinline__ float red16_max(float x) {
    DPP_STEP(x, 0xB1, fmaxf); DPP_STEP(x, 0x4E, fmaxf);
    DPP_STEP(x, 0x141, fmaxf); DPP_STEP(x, 0x140, fmaxf);
    return x;
}
__device__ __forceinline__ float addf(float a, float b) { return a + b; }
__device__ __forceinline__ float red16_sum(float x) {
    DPP_STEP(x, 0xB1, addf); DPP_STEP(x, 0x4E, addf);
    DPP_STEP(x, 0x141, addf); DPP_STEP(x, 0x140, addf);
    return x;
}

// softmax scale folded into Q at projection time: 1/sqrt(128) * log2(e)
#define QSC (0.0883883476f * 1.4426950408f)

// ---------------------------------------------------------------------------
// Kernel 1: W [1024][128] fp32 -> Wt [3*128][1024] bf16 (transposed, converted)
// ---------------------------------------------------------------------------
__global__ __launch_bounds__(256) void k_wt(const float* __restrict__ Wk,
                                            const float* __restrict__ Wq,
                                            const float* __restrict__ Wv,
                                            unsigned short* __restrict__ Wt) {
    __shared__ float tile[64][65];
    int w = blockIdx.z;  // 0=K, 1=Q, 2=V
    const float* W = (w == 0) ? Wk : (w == 1) ? Wq : Wv;
    int c0 = blockIdx.x * 64, h0 = blockIdx.y * 64;
    int tid = threadIdx.x;
#pragma unroll
    for (int k = 0; k < 16; k++) {
        int idx = tid + k * 256;
        int r = idx >> 6, c = idx & 63;
        tile[r][c] = W[(size_t)(c0 + r) * H_ + h0 + c];
    }
    __syncthreads();
#pragma unroll
    for (int k = 0; k < 16; k++) {
        int idx = tid + k * 256;
        int hh = idx >> 6, cc = idx & 63;
        Wt[(size_t)(w * H_ + h0 + hh) * C_ + c0 + cc] = f2bf(tile[cc][hh]);
    }
}

// ---------------------------------------------------------------------------
// Kernel 2: fused QKV GEMM — r4 PROVEN version (64-row tiles).
// 512 blocks: 256 row-tiles (64 rows) x 2 col-halves (192 cols).
// Register ping-pong of x chunk + Wt fragments. bounds(256,2): no spill.
// ---------------------------------------------------------------------------
__global__ __launch_bounds__(256, 2) void k_qkv(const float* __restrict__ x,
                                                const unsigned short* __restrict__ Wt,
                                                unsigned short* __restrict__ Qb,
                                                unsigned short* __restrict__ Kb,
                                                unsigned short* __restrict__ Vt) {
    __shared__ unsigned short a_lds[64 * 72];  // 64 rows x 64 k, stride 72
    int tid = threadIdx.x;
    int wv = tid >> 6, lane = tid & 63, quad = lane >> 4, lo = lane & 15;
    int r0 = blockIdx.x * 64;
    int cb = blockIdx.y;
    int nt0 = wv * 3;

    f32x4 acc[3][4];
#pragma unroll
    for (int i = 0; i < 3; i++)
#pragma unroll
        for (int j = 0; j < 4; j++) acc[i][j] = (f32x4){0.f, 0.f, 0.f, 0.f};

    const int row_s = tid >> 2;
    const int seg_s = (tid & 3) * 16;
    size_t xbase = (size_t)(r0 + row_s) * C_ + seg_s;

    const unsigned short* wp[3];
#pragma unroll
    for (int nt = 0; nt < 3; nt++)
        wp[nt] = Wt + (size_t)(cb * 192 + (nt0 + nt) * 16 + lo) * C_ + quad * 8;

    auto pack_store = [&](const float4 (&f)[4]) {
        uint4 u0, u1;
        u0.x = (unsigned)f2bf(f[0].x) | ((unsigned)f2bf(f[0].y) << 16);
        u0.y = (unsigned)f2bf(f[0].z) | ((unsigned)f2bf(f[0].w) << 16);
        u0.z = (unsigned)f2bf(f[1].x) | ((unsigned)f2bf(f[1].y) << 16);
        u0.w = (unsigned)f2bf(f[1].z) | ((unsigned)f2bf(f[1].w) << 16);
        u1.x = (unsigned)f2bf(f[2].x) | ((unsigned)f2bf(f[2].y) << 16);
        u1.y = (unsigned)f2bf(f[2].z) | ((unsigned)f2bf(f[2].w) << 16);
        u1.z = (unsigned)f2bf(f[3].x) | ((unsigned)f2bf(f[3].y) << 16);
        u1.w = (unsigned)f2bf(f[3].z) | ((unsigned)f2bf(f[3].w) << 16);
        *(uint4*)&a_lds[row_s * 72 + seg_s] = u0;
        *(uint4*)&a_lds[row_s * 72 + seg_s + 8] = u1;
    };
    auto load_x = [&](float4 (&f)[4], int kc) {
        const float* xp = x + xbase + kc * 64;
#pragma unroll
        for (int j = 0; j < 4; j++) f[j] = *(const float4*)(xp + j * 4);
    };
    auto load_b = [&](s16x8 (&b)[3][2], int kc) {
#pragma unroll
        for (int nt = 0; nt < 3; nt++)
#pragma unroll
            for (int kh = 0; kh < 2; kh++)
                b[nt][kh] = *(const s16x8*)(wp[nt] + kc * 64 + kh * 32);
    };
    auto gemm = [&](const s16x8 (&b)[3][2]) {
        s16x8 af[4][2];
#pragma unroll
        for (int mt = 0; mt < 4; mt++)
#pragma unroll
            for (int kh = 0; kh < 2; kh++)
                af[mt][kh] = *(const s16x8*)&a_lds[(mt * 16 + lo) * 72 + kh * 32 + quad * 8];
#pragma unroll
        for (int nt = 0; nt < 3; nt++)
#pragma unroll
            for (int kh = 0; kh < 2; kh++)
#pragma unroll
                for (int mt = 0; mt < 4; mt++)
                    acc[nt][mt] = __builtin_amdgcn_mfma_f32_16x16x32_bf16(
                        af[mt][kh], b[nt][kh], acc[nt][mt], 0, 0, 0);
    };

    float4 xa[4], xb[4];
    s16x8 ba[3][2], bb[3][2];
    load_x(xa, 0);
    load_b(ba, 0);

    for (int kc2 = 0; kc2 < 8; kc2++) {
        int e = kc2 * 2;
        pack_store(xa);
        load_x(xb, e + 1);
        __syncthreads();
        load_b(bb, e + 1);
        gemm(ba);
        __syncthreads();
        pack_store(xb);
        if (kc2 < 7) load_x(xa, e + 2);
        __syncthreads();
        if (kc2 < 7) load_b(ba, e + 2);
        gemm(bb);
        __syncthreads();
    }

    // Epilogue. C-layout: row = mt*16 + quad*4 + r, col = cb*192 + (nt0+nt)*16 + lo
#pragma unroll
    for (int nt = 0; nt < 3; nt++) {
        int col = cb * 192 + (nt0 + nt) * 16 + lo;
        int w = col >> 7, h = col & 127;
#pragma unroll
        for (int mt = 0; mt < 4; mt++) {
            int mrow = r0 + mt * 16 + quad * 4;
            if (w == 2) {
                int b = mrow >> 12, t = mrow & 4095;
                uint2 pk;
                pk.x = (unsigned)f2bf(acc[nt][mt][0]) | ((unsigned)f2bf(acc[nt][mt][1]) << 16);
                pk.y = (unsigned)f2bf(acc[nt][mt][2]) | ((unsigned)f2bf(acc[nt][mt][3]) << 16);
                *(uint2*)(Vt + (size_t)(b * H_ + h) * T_ + t) = pk;
            } else if (w == 1) {
                unsigned short* dst = Qb + (size_t)mrow * H_ + h;
#pragma unroll
                for (int r = 0; r < 4; r++)
                    dst[(size_t)r * H_] = f2bf(acc[nt][mt][r] * QSC);
            } else {
                unsigned short* dst = Kb + (size_t)mrow * H_ + h;
#pragma unroll
                for (int r = 0; r < 4; r++)
                    dst[(size_t)r * H_] = f2bf(acc[nt][mt][r]);
            }
        }
    }
}

// ---------------------------------------------------------------------------
// Kernel 3: causal flash attention, split-KV, register prefetch (explicit
// scalars), DPP softmax, truncation P-pack, rescale-skip.
// bounds(256,3) — NOT 4: gfx950 unified VGPR+AGPR file means true usage is
// CSV VGPR_Count (~84) PLUS AGPRs (~64-80) ≈ 150-165; the (256,4) cap of 128
// spilled to scratch (r6: WRITE_SIZE 38->147 MB). (256,3) cap ~170 fits.
// ---------------------------------------------------------------------------
#define LOAD_KV(kv0)                                                            \
    do {                                                                        \
        const uint4* kg = (const uint4*)(Kb + (size_t)(batch * T_ + (kv0) + srow_k) * H_); \
        pk0 = kg[sseg_k + 0]; pk1 = kg[sseg_k + 1];                             \
        pk2 = kg[sseg_k + 2]; pk3 = kg[sseg_k + 3];                             \
        const uint4* vg = (const uint4*)(Vt + (size_t)(batch * H_ + srow_v) * T_ + (kv0)); \
        pv0 = vg[sseg_v + 0]; pv1 = vg[sseg_v + 1];                             \
        pv2 = vg[sseg_v + 2]; pv3 = vg[sseg_v + 3];                             \
    } while (0)

template <int NSPLIT>
__global__ __launch_bounds__(256, 3) void k_attn(const unsigned short* __restrict__ Qb,
                                                 const unsigned short* __restrict__ Kb,
                                                 const unsigned short* __restrict__ Vt,
                                                 float* __restrict__ Opart,
                                                 float* __restrict__ Mpart,
                                                 float* __restrict__ Lpart,
                                                 float* __restrict__ out) {
    __shared__ uint4 kbuf[64 * 16];
    __shared__ uint4 vbuf[128 * 8];
    __shared__ unsigned short pbuf[4][16 * 64];

    int tid = threadIdx.x;
    int wv = tid >> 6, lane = tid & 63, quad = lane >> 4, lo = lane & 15;

    int id = blockIdx.x;
    int qt = 63 - id / (4 * NSPLIT);   // largest-first
    int rem = id % (4 * NSPLIT);
    int batch = rem / NSPLIT;
    int split = rem % NSPLIT;
    int m0 = qt * 64 + wv * 16;

    s16x8 qf[4];
    size_t qrow = (size_t)(batch * T_ + m0 + lo) * H_;
#pragma unroll
    for (int ks = 0; ks < 4; ks++)
        qf[ks] = *(const s16x8*)(Qb + qrow + ks * 32 + quad * 8);

    f32x4 acc_o[8];
#pragma unroll
    for (int o = 0; o < 8; o++) acc_o[o] = (f32x4){0.f, 0.f, 0.f, 0.f};
    float m_i[4], l_i[4];
#pragma unroll
    for (int r = 0; r < 4; r++) { m_i[r] = -INFINITY; l_i[r] = 0.f; }

    const int srow_k = tid >> 2, sseg_k = (tid & 3) * 4;
    const int srow_v = tid >> 1, sseg_v = (tid & 1) * 4;

    uint4 pk0, pk1, pk2, pk3, pv0, pv1, pv2, pv3;
    if (split <= qt) LOAD_KV(split * 64);

    for (int t = split; t <= qt; t += NSPLIT) {
        int kv0 = t * 64;
        kbuf[srow_k * 16 + ((sseg_k + 0) ^ (srow_k & 15))] = pk0;
        kbuf[srow_k * 16 + ((sseg_k + 1) ^ (srow_k & 15))] = pk1;
        kbuf[srow_k * 16 + ((sseg_k + 2) ^ (srow_k & 15))] = pk2;
        kbuf[srow_k * 16 + ((sseg_k + 3) ^ (srow_k & 15))] = pk3;
        vbuf[srow_v * 8 + ((sseg_v + 0) ^ (srow_v & 7))] = pv0;
        vbuf[srow_v * 8 + ((sseg_v + 1) ^ (srow_v & 7))] = pv1;
        vbuf[srow_v * 8 + ((sseg_v + 2) ^ (srow_v & 7))] = pv2;
        vbuf[srow_v * 8 + ((sseg_v + 3) ^ (srow_v & 7))] = pv3;
        __syncthreads();
        if (t + NSPLIT <= qt) LOAD_KV((t + NSPLIT) * 64);

        // S = Q K^T (logits already in log2 domain; Q pre-scaled)
        f32x4 s_acc[4];
#pragma unroll
        for (int nt = 0; nt < 4; nt++) s_acc[nt] = (f32x4){0.f, 0.f, 0.f, 0.f};
#pragma unroll
        for (int ks = 0; ks < 4; ks++) {
#pragma unroll
            for (int nt = 0; nt < 4; nt++) {
                s16x8 kf = as_frag(kbuf[(nt * 16 + lo) * 16 + ((ks * 4 + quad) ^ lo)]);
                s_acc[nt] = __builtin_amdgcn_mfma_f32_16x16x32_bf16(qf[ks], kf, s_acc[nt], 0, 0, 0);
            }
        }

        float p[4][4];
        bool diag = (t == qt);
#pragma unroll
        for (int nt = 0; nt < 4; nt++)
#pragma unroll
            for (int r = 0; r < 4; r++) {
                float sv = s_acc[nt][r];
                if (diag) {
                    int colg = kv0 + nt * 16 + lo;
                    int rowg = m0 + quad * 4 + r;
                    if (colg > rowg) sv = -INFINITY;
                }
                p[nt][r] = sv;
            }
        float mnew[4];
        bool upd = false;
#pragma unroll
        for (int r = 0; r < 4; r++) {
            float mx = fmaxf(fmaxf(p[0][r], p[1][r]), fmaxf(p[2][r], p[3][r]));
            mx = red16_max(mx);
            mnew[r] = fmaxf(m_i[r], mx);
            upd |= (mnew[r] > m_i[r]);
        }
        // wave-uniform rescale-skip: running max usually stops moving after
        // the first few tiles -> most iterations skip the alpha rescale.
        if (__any(upd)) {
#pragma unroll
            for (int r = 0; r < 4; r++) {
                float alpha = exp2f(m_i[r] - mnew[r]);
                l_i[r] *= alpha;
                m_i[r] = mnew[r];
#pragma unroll
                for (int o = 0; o < 8; o++) acc_o[o][r] *= alpha;
            }
        }
        float rs[4] = {0.f, 0.f, 0.f, 0.f};
#pragma unroll
        for (int nt = 0; nt < 4; nt++)
#pragma unroll
            for (int r = 0; r < 4; r++) {
                float pv = exp2f(p[nt][r] - mnew[r]);
                p[nt][r] = pv;
                rs[r] += pv;
            }
#pragma unroll
        for (int r = 0; r < 4; r++) l_i[r] += red16_sum(rs[r]);

        // P: C-layout -> A-layout via per-wave LDS. Truncation pack (P in
        // [0,1], err <= 2^-9): 1 VALU op.
        unsigned short* pb = pbuf[wv];
#pragma unroll
        for (int nt = 0; nt < 4; nt++)
#pragma unroll
            for (int r = 0; r < 4; r++) {
                int prow = quad * 4 + r;
                int col = nt * 16 + lo;
                int seg = col >> 3, off = col & 7;
                pb[prow * 64 + ((seg ^ (prow & 7)) << 3) + off] =
                    (unsigned short)(__float_as_uint(p[nt][r]) >> 16);
            }
        s16x8 pf[2];
#pragma unroll
        for (int kss = 0; kss < 2; kss++) {
            int seg = kss * 4 + quad;
            pf[kss] = *(const s16x8*)&pb[lo * 64 + ((seg ^ (lo & 7)) << 3)];
        }

#pragma unroll
        for (int kss = 0; kss < 2; kss++)
#pragma unroll
            for (int o = 0; o < 8; o++) {
                int vrow = o * 16 + lo;
                s16x8 vf = as_frag(vbuf[vrow * 8 + ((kss * 4 + quad) ^ (vrow & 7))]);
                acc_o[o] = __builtin_amdgcn_mfma_f32_16x16x32_bf16(pf[kss], vf, acc_o[o], 0, 0, 0);
            }
        __syncthreads();
    }

    if (NSPLIT == 1) {
        float inv[4];
#pragma unroll
        for (int r = 0; r < 4; r++) inv[r] = 1.0f / l_i[r];
#pragma unroll
        for (int o = 0; o < 8; o++)
#pragma unroll
            for (int r = 0; r < 4; r++) {
                int rowg = batch * T_ + m0 + quad * 4 + r;
                out[(size_t)rowg * H_ + o * 16 + lo] = acc_o[o][r] * inv[r];
            }
    } else {
        float* Op = Opart + (size_t)split * (16384 * 128);
#pragma unroll
        for (int o = 0; o < 8; o++)
#pragma unroll
            for (int r = 0; r < 4; r++) {
                int rowg = batch * T_ + m0 + quad * 4 + r;
                Op[(size_t)rowg * H_ + o * 16 + lo] = acc_o[o][r];
            }
        if (lo == 0) {
#pragma unroll
            for (int r = 0; r < 4; r++) {
                int rowg = batch * T_ + m0 + quad * 4 + r;
                Mpart[split * 16384 + rowg] = m_i[r];
                Lpart[split * 16384 + rowg] = l_i[r];
            }
        }
    }
}

// ---------------------------------------------------------------------------
// Kernel 4: combine split-KV partials. 8 rows/block, float4 per thread.
// ---------------------------------------------------------------------------
template <int NSPLIT>
__global__ __launch_bounds__(256) void k_comb(const float* __restrict__ Opart,
                                              const float* __restrict__ Mpart,
                                              const float* __restrict__ Lpart,
                                              float* __restrict__ out) {
    int tid = threadIdx.x;
    int row = blockIdx.x * 8 + (tid >> 5);
    int h4 = (tid & 31) * 4;
    float m[NSPLIT], l[NSPLIT];
    float M = -INFINITY;
#pragma unroll
    for (int s = 0; s < NSPLIT; s++) {
        m[s] = Mpart[s * 16384 + row];
        l[s] = Lpart[s * 16384 + row];
        M = fmaxf(M, m[s]);
    }
    float4 o = {0.f, 0.f, 0.f, 0.f};
    float den = 0.f;
#pragma unroll
    for (int s = 0; s < NSPLIT; s++) {
        float w = exp2f(m[s] - M);
        den += w * l[s];
        float4 v = *(const float4*)(Opart + ((size_t)s * 16384 + row) * H_ + h4);
        o.x += w * v.x; o.y += w * v.y; o.z += w * v.z; o.w += w * v.w;
    }
    float inv = 1.0f / den;
    float4 r = {o.x * inv, o.y * inv, o.z * inv, o.w * inv};
    *(float4*)(out + (size_t)row * H_ + h4) = r;
}

// ---------------------------------------------------------------------------
extern "C" void kernel_launch(void* const* d_in, const int* in_sizes, int n_in,
                              void* d_out, int out_size, void* d_ws, size_t ws_size,
                              hipStream_t stream) {
    const float* x  = (const float*)d_in[0];
    const float* Wk = (const float*)d_in[1];
    const float* Wq = (const float*)d_in[2];
    const float* Wv = (const float*)d_in[3];
    char* ws = (char*)d_ws;
    unsigned short* Wt = (unsigned short*)ws;                 // 768 KB
    unsigned short* Qb = (unsigned short*)(ws + (1u << 20));  // 4 MB
    unsigned short* Kb = (unsigned short*)(ws + (5u << 20));  // 4 MB
    unsigned short* Vt = (unsigned short*)(ws + (9u << 20));  // 4 MB -> end 13 MB
    float* out = (float*)d_out;

    const size_t SPLIT_O = (size_t)16384 * 128 * 4;  // 8 MB per split
    const size_t base = (size_t)13 << 20;
    const size_t need4 = base + 4 * SPLIT_O + 8 * 65536;
    const size_t need2 = base + 2 * SPLIT_O + 4 * 65536;

    k_wt  <<<dim3(16, 2, 3), 256, 0, stream>>>(Wk, Wq, Wv, Wt);
    k_qkv <<<dim3(256, 2), 256, 0, stream>>>(x, Wt, Qb, Kb, Vt);

    if (ws_size >= need4) {
        float* Op = (float*)(ws + base);
        float* Mp = (float*)(ws + base + 4 * SPLIT_O);
        float* Lp = (float*)(ws + base + 4 * SPLIT_O + 4 * 65536);
        k_attn<4><<<1024, 256, 0, stream>>>(Qb, Kb, Vt, Op, Mp, Lp, out);
        k_comb<4><<<2048, 256, 0, stream>>>(Op, Mp, Lp, out);
    } else if (ws_size >= need2) {
        float* Op = (float*)(ws + base);
        float* Mp = (float*)(ws + base + 2 * SPLIT_O);
        float* Lp = (float*)(ws + base + 2 * SPLIT_O + 2 * 65536);
        k_attn<2><<<512, 256, 0, stream>>>(Qb, Kb, Vt, Op, Mp, Lp, out);
        k_comb<2><<<2048, 256, 0, stream>>>(Op, Mp, Lp, out);
    } else {
        k_attn<1><<<256, 256, 0, stream>>>(Qb, Kb, Vt, nullptr, nullptr, nullptr, out);
    }
}

// Round 8
// 167.565 us; speedup vs baseline: 1.5392x; 1.0524x over previous
//
#include <hip/hip_runtime.h>
#include <stdint.h>
#include <math.h>

#define B_ 4
#define T_ 4096
#define C_ 1024
#define H_ 128

typedef __attribute__((ext_vector_type(8))) short s16x8;   // 8 bf16 (4 VGPRs)
typedef __attribute__((ext_vector_type(4))) float f32x4;   // MFMA accumulator

__device__ __forceinline__ unsigned short f2bf(float f) {
    union { float f; unsigned u; } v; v.f = f;
    unsigned r = v.u + 0x7fffu + ((v.u >> 16) & 1u);
    return (unsigned short)(r >> 16);
}

__device__ __forceinline__ s16x8 as_frag(uint4 u) {
    union { uint4 u; s16x8 s; } v; v.u = u; return v.s;
}

// softmax scale folded into Q at projection time: 1/sqrt(128) * log2(e)
#define QSC (0.0883883476f * 1.4426950408f)

// ---------------------------------------------------------------------------
// Kernel 1: W [1024][128] fp32 -> Wt [3*128][1024] bf16 (transposed, converted)
// ---------------------------------------------------------------------------
__global__ __launch_bounds__(256) void k_wt(const float* __restrict__ Wk,
                                            const float* __restrict__ Wq,
                                            const float* __restrict__ Wv,
                                            unsigned short* __restrict__ Wt) {
    __shared__ float tile[64][65];
    int w = blockIdx.z;  // 0=K, 1=Q, 2=V
    const float* W = (w == 0) ? Wk : (w == 1) ? Wq : Wv;
    int c0 = blockIdx.x * 64, h0 = blockIdx.y * 64;
    int tid = threadIdx.x;
#pragma unroll
    for (int k = 0; k < 16; k++) {
        int idx = tid + k * 256;
        int r = idx >> 6, c = idx & 63;
        tile[r][c] = W[(size_t)(c0 + r) * H_ + h0 + c];
    }
    __syncthreads();
#pragma unroll
    for (int k = 0; k < 16; k++) {
        int idx = tid + k * 256;
        int hh = idx >> 6, cc = idx & 63;
        Wt[(size_t)(w * H_ + h0 + hh) * C_ + c0 + cc] = f2bf(tile[cc][hh]);
    }
}

// ---------------------------------------------------------------------------
// Kernel 2: fused QKV GEMM, LDS double-buffer, ONE barrier per 64-K chunk
// (r7 structure had 2 barriers/chunk whose vmcnt(0) drained the just-issued
// HBM prefetch — the m97 structural stall). (256,3): ~115 live regs < 170.
// V is written t-PERMUTED within each 32-block: pos = 8*((t&15)>>2) +
// 4*((t>>4)&1) + (t&3) — consumed by k_attn's PV fragment order.
// ---------------------------------------------------------------------------
__global__ __launch_bounds__(256, 3) void k_qkv(const float* __restrict__ x,
                                                const unsigned short* __restrict__ Wt,
                                                unsigned short* __restrict__ Qb,
                                                unsigned short* __restrict__ Kb,
                                                unsigned short* __restrict__ Vt) {
    __shared__ unsigned short a_lds[2][64 * 72];  // 2 x 9216 B
    int tid = threadIdx.x;
    int wv = tid >> 6, lane = tid & 63, quad = lane >> 4, lo = lane & 15;
    int r0 = blockIdx.x * 64;
    int cb = blockIdx.y;
    int nt0 = wv * 3;

    f32x4 acc[3][4];
#pragma unroll
    for (int i = 0; i < 3; i++)
#pragma unroll
        for (int j = 0; j < 4; j++) acc[i][j] = (f32x4){0.f, 0.f, 0.f, 0.f};

    const int row_s = tid >> 2;
    const int seg_s = (tid & 3) * 16;
    size_t xbase = (size_t)(r0 + row_s) * C_ + seg_s;

    const unsigned short* wp[3];
#pragma unroll
    for (int nt = 0; nt < 3; nt++)
        wp[nt] = Wt + (size_t)(cb * 192 + (nt0 + nt) * 16 + lo) * C_ + quad * 8;

    auto pack_store = [&](unsigned short* buf, const float4 (&f)[4]) {
        uint4 u0, u1;
        u0.x = (unsigned)f2bf(f[0].x) | ((unsigned)f2bf(f[0].y) << 16);
        u0.y = (unsigned)f2bf(f[0].z) | ((unsigned)f2bf(f[0].w) << 16);
        u0.z = (unsigned)f2bf(f[1].x) | ((unsigned)f2bf(f[1].y) << 16);
        u0.w = (unsigned)f2bf(f[1].z) | ((unsigned)f2bf(f[1].w) << 16);
        u1.x = (unsigned)f2bf(f[2].x) | ((unsigned)f2bf(f[2].y) << 16);
        u1.y = (unsigned)f2bf(f[2].z) | ((unsigned)f2bf(f[2].w) << 16);
        u1.z = (unsigned)f2bf(f[3].x) | ((unsigned)f2bf(f[3].y) << 16);
        u1.w = (unsigned)f2bf(f[3].z) | ((unsigned)f2bf(f[3].w) << 16);
        *(uint4*)&buf[row_s * 72 + seg_s] = u0;
        *(uint4*)&buf[row_s * 72 + seg_s + 8] = u1;
    };
    auto load_x = [&](float4 (&f)[4], int kc) {
        const float* xp = x + xbase + kc * 64;
#pragma unroll
        for (int j = 0; j < 4; j++) f[j] = *(const float4*)(xp + j * 4);
    };

    float4 xr[4];
    load_x(xr, 0);
    pack_store(a_lds[0], xr);
    __syncthreads();

    for (int kc = 0; kc < 16; kc++) {
        const unsigned short* buf = a_lds[kc & 1];
        float4 xn[4];
        if (kc < 15) load_x(xn, kc + 1);  // HBM prefetch; lands during gemm
        s16x8 b[3][2];
#pragma unroll
        for (int nt = 0; nt < 3; nt++)
#pragma unroll
            for (int kh = 0; kh < 2; kh++)
                b[nt][kh] = *(const s16x8*)(wp[nt] + kc * 64 + kh * 32);
        s16x8 af[4][2];
#pragma unroll
        for (int mt = 0; mt < 4; mt++)
#pragma unroll
            for (int kh = 0; kh < 2; kh++)
                af[mt][kh] = *(const s16x8*)&buf[(mt * 16 + lo) * 72 + kh * 32 + quad * 8];
#pragma unroll
        for (int nt = 0; nt < 3; nt++)
#pragma unroll
            for (int kh = 0; kh < 2; kh++)
#pragma unroll
                for (int mt = 0; mt < 4; mt++)
                    acc[nt][mt] = __builtin_amdgcn_mfma_f32_16x16x32_bf16(
                        af[mt][kh], b[nt][kh], acc[nt][mt], 0, 0, 0);
        if (kc < 15) pack_store((unsigned short*)a_lds[(kc & 1) ^ 1], xn);
        __syncthreads();  // next buf ready AND current buf's reads done
    }

    // Epilogue. C-layout: row = mt*16 + quad*4 + r, col = cb*192 + (nt0+nt)*16 + lo
#pragma unroll
    for (int nt = 0; nt < 3; nt++) {
        int col = cb * 192 + (nt0 + nt) * 16 + lo;
        int w = col >> 7, h = col & 127;
#pragma unroll
        for (int mt = 0; mt < 4; mt++) {
            int mrow = r0 + mt * 16 + quad * 4;
            if (w == 2) {
                int b = mrow >> 12, t0 = mrow & 4095;
                // permuted t within 32-block (see k_attn PV fragment order)
                int tp = (t0 & ~31) + (((t0 & 15) >> 2) << 3) + (((t0 >> 4) & 1) << 2);
                uint2 pk;
                pk.x = (unsigned)f2bf(acc[nt][mt][0]) | ((unsigned)f2bf(acc[nt][mt][1]) << 16);
                pk.y = (unsigned)f2bf(acc[nt][mt][2]) | ((unsigned)f2bf(acc[nt][mt][3]) << 16);
                *(uint2*)(Vt + (size_t)(b * H_ + h) * T_ + tp) = pk;
            } else if (w == 1) {
                unsigned short* dst = Qb + (size_t)mrow * H_ + h;
#pragma unroll
                for (int r = 0; r < 4; r++)
                    dst[(size_t)r * H_] = f2bf(acc[nt][mt][r] * QSC);
            } else {
                unsigned short* dst = Kb + (size_t)mrow * H_ + h;
#pragma unroll
                for (int r = 0; r < 4; r++)
                    dst[(size_t)r * H_] = f2bf(acc[nt][mt][r]);
            }
        }
    }
}

// ---------------------------------------------------------------------------
// Kernel 3: causal flash attention, S^T formulation (no P LDS round-trip).
// S^T = mfma(kf, qf): lane holds S[query=lo][key=nt*16+quad*4+r] -> softmax
// state is ONE scalar (m,l) per lane; cross-quad reduction = 2 shfl_xor.
// P packs directly into B-fragments; PV: O^T = mfma(vf, pf) with V staged
// key-permuted (pi(quad,j) = 16*(j>>2)+4*quad+(j&3), same bijection on both
// operands -> contraction unchanged). acc is per-query=lo -> scalar rescale.
// (256,3): ~145 live regs (VGPR+AGPR unified) < 170 cap.
// ---------------------------------------------------------------------------
#define LOAD_KV(kv0)                                                            \
    do {                                                                        \
        const uint4* kg = (const uint4*)(Kb + (size_t)(batch * T_ + (kv0) + srow_k) * H_); \
        pk0 = kg[sseg_k + 0]; pk1 = kg[sseg_k + 1];                             \
        pk2 = kg[sseg_k + 2]; pk3 = kg[sseg_k + 3];                             \
        const uint4* vg = (const uint4*)(Vt + (size_t)(batch * H_ + srow_v) * T_ + (kv0)); \
        pv0 = vg[sseg_v + 0]; pv1 = vg[sseg_v + 1];                             \
        pv2 = vg[sseg_v + 2]; pv3 = vg[sseg_v + 3];                             \
    } while (0)

template <int NSPLIT>
__global__ __launch_bounds__(256, 3) void k_attn(const unsigned short* __restrict__ Qb,
                                                 const unsigned short* __restrict__ Kb,
                                                 const unsigned short* __restrict__ Vt,
                                                 float* __restrict__ Opart,
                                                 float* __restrict__ Mpart,
                                                 float* __restrict__ Lpart,
                                                 float* __restrict__ out) {
    __shared__ uint4 kbuf[64 * 16];   // 16 KB
    __shared__ uint4 vbuf[128 * 8];   // 16 KB (t-permuted V^T rows)

    int tid = threadIdx.x;
    int wv = tid >> 6, lane = tid & 63, quad = lane >> 4, lo = lane & 15;

    int id = blockIdx.x;
    int qt = 63 - id / (4 * NSPLIT);   // largest-first
    int rem = id % (4 * NSPLIT);
    int batch = rem / NSPLIT;
    int split = rem % NSPLIT;
    int m0 = qt * 64 + wv * 16;
    int query = m0 + lo;

    s16x8 qf[4];
    size_t qrow = (size_t)(batch * T_ + m0 + lo) * H_;
#pragma unroll
    for (int ks = 0; ks < 4; ks++)
        qf[ks] = *(const s16x8*)(Qb + qrow + ks * 32 + quad * 8);

    f32x4 acc_o[8];   // O[query=lo][d = o*16 + quad*4 + r]
#pragma unroll
    for (int o = 0; o < 8; o++) acc_o[o] = (f32x4){0.f, 0.f, 0.f, 0.f};
    float m_i = -INFINITY, l_i = 0.f;

    const int srow_k = tid >> 2, sseg_k = (tid & 3) * 4;
    const int srow_v = tid >> 1, sseg_v = (tid & 1) * 4;

    uint4 pk0, pk1, pk2, pk3, pv0, pv1, pv2, pv3;
    if (split <= qt) LOAD_KV(split * 64);

    for (int t = split; t <= qt; t += NSPLIT) {
        int kv0 = t * 64;
        kbuf[srow_k * 16 + ((sseg_k + 0) ^ (srow_k & 15))] = pk0;
        kbuf[srow_k * 16 + ((sseg_k + 1) ^ (srow_k & 15))] = pk1;
        kbuf[srow_k * 16 + ((sseg_k + 2) ^ (srow_k & 15))] = pk2;
        kbuf[srow_k * 16 + ((sseg_k + 3) ^ (srow_k & 15))] = pk3;
        vbuf[srow_v * 8 + ((sseg_v + 0) ^ (srow_v & 7))] = pv0;
        vbuf[srow_v * 8 + ((sseg_v + 1) ^ (srow_v & 7))] = pv1;
        vbuf[srow_v * 8 + ((sseg_v + 2) ^ (srow_v & 7))] = pv2;
        vbuf[srow_v * 8 + ((sseg_v + 3) ^ (srow_v & 7))] = pv3;
        __syncthreads();
        if (t + NSPLIT <= qt) LOAD_KV((t + NSPLIT) * 64);

        // S^T = K Q^T: lane holds S[query=lo][key = kv0 + nt*16 + quad*4 + r]
        f32x4 s_acc[4];
#pragma unroll
        for (int nt = 0; nt < 4; nt++) s_acc[nt] = (f32x4){0.f, 0.f, 0.f, 0.f};
#pragma unroll
        for (int ks = 0; ks < 4; ks++) {
#pragma unroll
            for (int nt = 0; nt < 4; nt++) {
                s16x8 kf = as_frag(kbuf[(nt * 16 + lo) * 16 + ((ks * 4 + quad) ^ lo)]);
                s_acc[nt] = __builtin_amdgcn_mfma_f32_16x16x32_bf16(kf, qf[ks], s_acc[nt], 0, 0, 0);
            }
        }

        float p[4][4];
        bool diag = (t == qt);
#pragma unroll
        for (int nt = 0; nt < 4; nt++)
#pragma unroll
            for (int r = 0; r < 4; r++) {
                float sv = s_acc[nt][r];
                if (diag && (kv0 + nt * 16 + quad * 4 + r > query)) sv = -INFINITY;
                p[nt][r] = sv;
            }

        float mx = p[0][0];
#pragma unroll
        for (int nt = 0; nt < 4; nt++)
#pragma unroll
            for (int r = 0; r < 4; r++) mx = fmaxf(mx, p[nt][r]);
        mx = fmaxf(mx, __shfl_xor(mx, 16));
        mx = fmaxf(mx, __shfl_xor(mx, 32));
        float mnew = fmaxf(m_i, mx);
        // wave-uniform rescale-skip
        if (__any(mnew > m_i)) {
            float alpha = exp2f(m_i - mnew);
            l_i *= alpha;
            m_i = mnew;
#pragma unroll
            for (int o = 0; o < 8; o++)
#pragma unroll
                for (int r = 0; r < 4; r++) acc_o[o][r] *= alpha;
        }
        float rs = 0.f;
#pragma unroll
        for (int nt = 0; nt < 4; nt++)
#pragma unroll
            for (int r = 0; r < 4; r++) {
                float pv = exp2f(p[nt][r] - mnew);
                p[nt][r] = pv;
                rs += pv;
            }
        rs += __shfl_xor(rs, 16);
        rs += __shfl_xor(rs, 32);
        l_i += rs;

        // pack P straight into B-fragments (truncation; P in [0,1])
        s16x8 pf[2];
#pragma unroll
        for (int kt = 0; kt < 2; kt++) {
            uint4 u;
            u.x = (__float_as_uint(p[2 * kt][0]) >> 16) | ((__float_as_uint(p[2 * kt][1]) >> 16) << 16);
            u.y = (__float_as_uint(p[2 * kt][2]) >> 16) | ((__float_as_uint(p[2 * kt][3]) >> 16) << 16);
            u.z = (__float_as_uint(p[2 * kt + 1][0]) >> 16) | ((__float_as_uint(p[2 * kt + 1][1]) >> 16) << 16);
            u.w = (__float_as_uint(p[2 * kt + 1][2]) >> 16) | ((__float_as_uint(p[2 * kt + 1][3]) >> 16) << 16);
            pf[kt] = as_frag(u);
        }

        // O^T += V^T P^T  (A = vf from permuted vbuf, B = pf)
#pragma unroll
        for (int kt = 0; kt < 2; kt++)
#pragma unroll
            for (int o = 0; o < 8; o++) {
                int vrow = o * 16 + lo;
                s16x8 vf = as_frag(vbuf[vrow * 8 + ((kt * 4 + quad) ^ (vrow & 7))]);
                acc_o[o] = __builtin_amdgcn_mfma_f32_16x16x32_bf16(vf, pf[kt], acc_o[o], 0, 0, 0);
            }
        __syncthreads();
    }

    int rowg = batch * T_ + m0 + lo;
    if (NSPLIT == 1) {
        float inv = 1.0f / l_i;
#pragma unroll
        for (int o = 0; o < 8; o++) {
            float4 v = {acc_o[o][0] * inv, acc_o[o][1] * inv,
                        acc_o[o][2] * inv, acc_o[o][3] * inv};
            *(float4*)(out + (size_t)rowg * H_ + o * 16 + quad * 4) = v;
        }
    } else {
        float* Op = Opart + (size_t)split * (16384 * 128);
#pragma unroll
        for (int o = 0; o < 8; o++) {
            float4 v = {acc_o[o][0], acc_o[o][1], acc_o[o][2], acc_o[o][3]};
            *(float4*)(Op + (size_t)rowg * H_ + o * 16 + quad * 4) = v;
        }
        if (quad == 0) {
            Mpart[split * 16384 + rowg] = m_i;
            Lpart[split * 16384 + rowg] = l_i;
        }
    }
}

// ---------------------------------------------------------------------------
// Kernel 4: combine split-KV partials. 8 rows/block, float4 per thread.
// ---------------------------------------------------------------------------
template <int NSPLIT>
__global__ __launch_bounds__(256) void k_comb(const float* __restrict__ Opart,
                                              const float* __restrict__ Mpart,
                                              const float* __restrict__ Lpart,
                                              float* __restrict__ out) {
    int tid = threadIdx.x;
    int row = blockIdx.x * 8 + (tid >> 5);
    int h4 = (tid & 31) * 4;
    float m[NSPLIT], l[NSPLIT];
    float M = -INFINITY;
#pragma unroll
    for (int s = 0; s < NSPLIT; s++) {
        m[s] = Mpart[s * 16384 + row];
        l[s] = Lpart[s * 16384 + row];
        M = fmaxf(M, m[s]);
    }
    float4 o = {0.f, 0.f, 0.f, 0.f};
    float den = 0.f;
#pragma unroll
    for (int s = 0; s < NSPLIT; s++) {
        float w = exp2f(m[s] - M);
        den += w * l[s];
        float4 v = *(const float4*)(Opart + ((size_t)s * 16384 + row) * H_ + h4);
        o.x += w * v.x; o.y += w * v.y; o.z += w * v.z; o.w += w * v.w;
    }
    float inv = 1.0f / den;
    float4 r = {o.x * inv, o.y * inv, o.z * inv, o.w * inv};
    *(float4*)(out + (size_t)row * H_ + h4) = r;
}

// ---------------------------------------------------------------------------
extern "C" void kernel_launch(void* const* d_in, const int* in_sizes, int n_in,
                              void* d_out, int out_size, void* d_ws, size_t ws_size,
                              hipStream_t stream) {
    const float* x  = (const float*)d_in[0];
    const float* Wk = (const float*)d_in[1];
    const float* Wq = (const float*)d_in[2];
    const float* Wv = (const float*)d_in[3];
    char* ws = (char*)d_ws;
    unsigned short* Wt = (unsigned short*)ws;                 // 768 KB
    unsigned short* Qb = (unsigned short*)(ws + (1u << 20));  // 4 MB
    unsigned short* Kb = (unsigned short*)(ws + (5u << 20));  // 4 MB
    unsigned short* Vt = (unsigned short*)(ws + (9u << 20));  // 4 MB -> end 13 MB
    float* out = (float*)d_out;

    const size_t SPLIT_O = (size_t)16384 * 128 * 4;  // 8 MB per split
    const size_t base = (size_t)13 << 20;
    const size_t need4 = base + 4 * SPLIT_O + 8 * 65536;
    const size_t need2 = base + 2 * SPLIT_O + 4 * 65536;

    k_wt  <<<dim3(16, 2, 3), 256, 0, stream>>>(Wk, Wq, Wv, Wt);
    k_qkv <<<dim3(256, 2), 256, 0, stream>>>(x, Wt, Qb, Kb, Vt);

    if (ws_size >= need4) {
        float* Op = (float*)(ws + base);
        float* Mp = (float*)(ws + base + 4 * SPLIT_O);
        float* Lp = (float*)(ws + base + 4 * SPLIT_O + 4 * 65536);
        k_attn<4><<<1024, 256, 0, stream>>>(Qb, Kb, Vt, Op, Mp, Lp, out);
        k_comb<4><<<2048, 256, 0, stream>>>(Op, Mp, Lp, out);
    } else if (ws_size >= need2) {
        float* Op = (float*)(ws + base);
        float* Mp = (float*)(ws + base + 2 * SPLIT_O);
        float* Lp = (float*)(ws + base + 2 * SPLIT_O + 2 * 65536);
        k_attn<2><<<512, 256, 0, stream>>>(Qb, Kb, Vt, Op, Mp, Lp, out);
        k_comb<2><<<2048, 256, 0, stream>>>(Op, Mp, Lp, out);
    } else {
        k_attn<1><<<256, 256, 0, stream>>>(Qb, Kb, Vt, nullptr, nullptr, nullptr, out);
    }
}